// Round 11
// baseline (408.712 us; speedup 1.0000x reference)
//
#include <hip/hip_runtime.h>

typedef __attribute__((ext_vector_type(8))) short short8;
typedef __attribute__((ext_vector_type(16))) float f32x16;

#define IROWS 144
#define ISTRIDE (IROWS * 128)      // shorts, phase-1 image buffer
#define I2ROWS 40
#define I2STRIDE (I2ROWS * 128)    // shorts, phase-2 image buffer

template<int N> struct IC { static constexpr int v = N; };

static __device__ __forceinline__ unsigned packbf(float hi, float lo) {
    return __builtin_amdgcn_perm(__float_as_uint(hi) + 0x8000u,
                                 __float_as_uint(lo) + 0x8000u, 0x07060302u);
}
static __device__ __forceinline__ unsigned short one_bf(float f) {
    return (unsigned short)((__float_as_uint(f) + 0x8000u) >> 16);
}
static __device__ __forceinline__ float bflo(unsigned u) { return __uint_as_float(u << 16); }
static __device__ __forceinline__ float bfhi(unsigned u) { return __uint_as_float(u & 0xffff0000u); }

// bf16 image swizzle: 16B-granular XOR (b128-safe, uint2-safe)
static __device__ __forceinline__ int swzB(int row, int c) {
    return row * 128 + (c ^ ((row & 15) << 3));
}
// fp32 master swizzle: 16B-granular XOR (float4-safe, float2-safe)
static __device__ __forceinline__ int swzH(int t, int o) {
    return (t * 128 + o) ^ ((t & 15) << 2);
}

// ================= PHASE 1: steps 0-7 (d=1,d=2), 32 blocks x 256 thr =================
__global__ __launch_bounds__(256, 1)
void vgt_phase1(const int* __restrict__ x,
                const float* __restrict__ emb_w,
                const float* __restrict__ red_w,
                const float* __restrict__ red_b,
                const float* __restrict__ conv_w,
                const float* __restrict__ conv_b,
                unsigned short* __restrict__ gw16)
{
    __shared__ short img[2 * ISTRIDE];     // 73728 B ping-pong
    __shared__ float hrF[129 * 128];       // 66048 B fp32 master (swizzled)
    __shared__ float m1S[128][10];
    __shared__ float m2S[128][10];
    __shared__ float cbS[128];
    __shared__ float rbS[128];
    __shared__ int   xbS[256];

    const int b    = blockIdx.x;
    const int tid  = threadIdx.x;
    const int lane = tid & 63;
    const int wv   = tid >> 6;          // 0..3
    const int mpair = wv & 1;           // o in [mpair*64, mpair*64+64)
    const int tgrp  = wv >> 1;          // 0 -> tiles {0,64,128pad}; 1 -> {32,96}
    const int obase = mpair * 64;
    const int l31  = lane & 31;
    const int lhi  = lane >> 5;

    for (int i = tid; i < ISTRIDE; i += 256) ((int*)img)[i] = 0;   // zero both buffers
    xbS[tid] = x[b * 256 + tid];
    if (tid < 128) { cbS[tid] = conv_b[tid]; rbS[tid] = red_b[tid]; }
    for (int e = tid; e < 2560; e += 256) {
        int o = e / 20, col = e % 20, v = col % 10;
        const float4* rw = (const float4*)(red_w + o * 256 + ((col < 10) ? 0 : 128));
        const float4* ew = (const float4*)(emb_w + v * 128);
        float s = 0.f;
#pragma unroll 8
        for (int c = 0; c < 32; ++c) {
            float4 a = rw[c], e4 = ew[c];
            s += a.x * e4.x + a.y * e4.y + a.z * e4.z + a.w * e4.w;
        }
        if (col < 10) m1S[o][v] = s; else m2S[o][v] = s;
    }

    // conv weights for BOTH m-tiles of this wave's pair: aw[(kk*8+cb)*2 + mt]  (192 VGPR)
    short8 aw[48];
#pragma unroll
    for (int s = 0; s < 24; ++s) {
        int kk = s >> 3, cb = s & 7;
        int c0 = cb * 16 + lhi * 8;
#pragma unroll
        for (int mt = 0; mt < 2; ++mt) {
            int o = obase + mt * 32 + l31;
            short8 v;
#pragma unroll
            for (int j = 0; j < 8; ++j)
                v[j] = (short)one_bf(conv_w[(o * 128 + c0 + j) * 3 + kk]);
            aw[s * 2 + mt] = v;
        }
    }
    __syncthreads();

    // initial h (t 0..127 real, t=128 zero) into hrF + img buffer 0
    for (int i = tid; i < 129 * 64; i += 256) {
        int t = i >> 6, o2 = (i & 63) * 2;
        float v0 = 0.f, v1 = 0.f;
        if (t < 128) {
            int xv1 = xbS[t], xv2 = xbS[t + 128];
            v0 = m1S[o2+0][xv1] + m2S[o2+0][xv2] + rbS[o2+0]; v0 = v0 > 0.f ? v0 : 0.f;
            v1 = m1S[o2+1][xv1] + m2S[o2+1][xv2] + rbS[o2+1]; v1 = v1 > 0.f ? v1 : 0.f;
            *(unsigned*)&img[swzB(t + 4, o2)] = packbf(v1, v0);
        }
        *(float2*)&hrF[swzH(t, o2)] = make_float2(v0, v1);
    }
    __syncthreads();

    int cur = 0;
    auto commit = [&](const f32x16& ac, int mt, int t, int row, short* dst) {
#pragma unroll
        for (int g = 0; g < 4; ++g) {
            int o4 = obase + mt * 32 + 8 * g + 4 * lhi;
            int hi = swzH(t, o4);
            float4 h4 = *(float4*)&hrF[hi];
            h4.x += fmaxf(ac[4*g+0], 0.f);
            h4.y += fmaxf(ac[4*g+1], 0.f);
            h4.z += fmaxf(ac[4*g+2], 0.f);
            h4.w += fmaxf(ac[4*g+3], 0.f);
            *(float4*)&hrF[hi] = h4;
            *(uint2*)&dst[swzB(row, o4)] = make_uint2(packbf(h4.y, h4.x), packbf(h4.w, h4.z));
        }
    };
    auto tileP1 = [&](auto DDC, int tcol, bool pad, const short* src, short* dst) {
        constexpr int DD = decltype(DDC)::v;
        f32x16 a0, a1;
#pragma unroll
        for (int g = 0; g < 4; ++g) {
            float4 b0 = *(const float4*)&cbS[obase + 8 * g + 4 * lhi];
            float4 b1 = *(const float4*)&cbS[obase + 32 + 8 * g + 4 * lhi];
            a0[4*g+0]=b0.x; a0[4*g+1]=b0.y; a0[4*g+2]=b0.z; a0[4*g+3]=b0.w;
            a1[4*g+0]=b1.x; a1[4*g+1]=b1.y; a1[4*g+2]=b1.z; a1[4*g+3]=b1.w;
        }
#pragma unroll
        for (int kk = 0; kk < 3; ++kk) {
            int row = tcol + 4 + l31 + (kk - 1) * DD;
            if (pad) row = row > 140 ? 140 : row;
#pragma unroll
            for (int cb = 0; cb < 8; ++cb) {
                short8 bf = *(const short8*)&src[swzB(row, cb * 16 + lhi * 8)];
                a0 = __builtin_amdgcn_mfma_f32_32x32x16_bf16(aw[(kk*8+cb)*2+0], bf, a0, 0, 0, 0);
                a1 = __builtin_amdgcn_mfma_f32_32x32x16_bf16(aw[(kk*8+cb)*2+1], bf, a1, 0, 0, 0);
            }
        }
        if (!pad || l31 == 0) {
            int t = pad ? 128 : tcol + l31;
            commit(a0, 0, t, t + 4, dst);
            commit(a1, 1, t, t + 4, dst);
        }
    };
    auto stepP1 = [&](auto DDC) {
        const short* src = img + cur * ISTRIDE;
        short*       dst = img + (cur ^ 1) * ISTRIDE;
        if (tgrp == 0) {
            tileP1(DDC, 0,  false, src, dst);
            tileP1(DDC, 64, false, src, dst);
            tileP1(DDC, 128, true, src, dst);
        } else {
            tileP1(DDC, 32, false, src, dst);
            tileP1(DDC, 96, false, src, dst);
        }
        __syncthreads();
        cur ^= 1;
    };
    for (int i = 0; i < 4; ++i) stepP1(IC<1>{});
    for (int i = 0; i < 4; ++i) stepP1(IC<2>{});

    // dump h (bf16) to global workspace: layout [t:129][o:128]
    for (int i = tid; i < 16512; i += 256) {
        int t = i >> 7, o = i & 127;
        gw16[b * 16512 + i] = one_bf(hrF[swzH(t, o)]);
    }
}

// ========== PHASE 2: 123 d=4 steps on residue lattices, 128 blocks x 256 thr ==========
__global__ __launch_bounds__(256, 1)
void vgt_phase2(const float* __restrict__ conv_w,
                const float* __restrict__ conv_b,
                const float* __restrict__ out_w,
                const float* __restrict__ out_b,
                const unsigned short* __restrict__ gw16,
                float* __restrict__ out)
{
    __shared__ short    img2[2 * I2STRIDE];   // 20480 B ping-pong
    __shared__ float    hrF2[33 * 128];       // 16896 B fp32 master (swizzled)
    __shared__ unsigned owP[10][64];
    __shared__ float    cbS[128];
    __shared__ float    obS[16];

    const int bid = blockIdx.x;
    const int b = bid >> 2, r = bid & 3;
    const int tid  = threadIdx.x;
    const int lane = tid & 63;
    const int wv   = tid >> 6;
    const bool mainw = (wv < 2);
    const int mpair = mainw ? wv : (wv - 2);
    const int obase = mpair * 64;
    const int l31  = lane & 31;
    const int lhi  = lane >> 5;

    for (int i = tid; i < I2STRIDE; i += 256) ((int*)img2)[i] = 0;
    if (tid < 128) cbS[tid] = conv_b[tid];
    if (tid < 16)  obS[tid] = (tid < 10) ? out_b[tid] : 0.f;
    for (int i = tid; i < 640; i += 256) {
        int v = i >> 6, j = i & 63;
        owP[v][j] = packbf(out_w[v * 128 + 2 * j + 1], out_w[v * 128 + 2 * j]);
    }

    // weights: main waves taps 0..2 (48 frags); appendix waves taps 0..1 (32 frags)
    short8 aw[48];
#pragma unroll
    for (int s = 0; s < 24; ++s) {
        int kk = s >> 3, cb = s & 7;
        if (!mainw && kk == 2) continue;
        int c0 = cb * 16 + lhi * 8;
#pragma unroll
        for (int mt = 0; mt < 2; ++mt) {
            int o = obase + mt * 32 + l31;
            short8 v;
#pragma unroll
            for (int j = 0; j < 8; ++j)
                v[j] = (short)one_bf(conv_w[(o * 128 + c0 + j) * 3 + kk]);
            aw[s * 2 + mt] = v;
        }
    }
    __syncthreads();   // img2 fully zeroed

    // init hrF2 + img2 buffer 0 from phase-1 dump
    const unsigned short* gb = gw16 + b * 16512;
    for (int i = tid; i < 33 * 64; i += 256) {
        int t = i >> 6, o2 = (i & 63) * 2;
        float v0 = 0.f, v1 = 0.f;
        if (t < 32) {
            v0 = bflo((unsigned)gb[(4 * t + r) * 128 + o2]);
            v1 = bflo((unsigned)gb[(4 * t + r) * 128 + o2 + 1]);
        } else if (r == 0) {
            v0 = bflo((unsigned)gb[16384 + o2]);
            v1 = bflo((unsigned)gb[16384 + o2 + 1]);
        }
        *(float2*)&hrF2[swzH(t, o2)] = make_float2(v0, v1);
        if (t < 32 || r == 0)
            *(unsigned*)&img2[swzB(t + 1, o2)] = packbf(v1, v0);
    }
    __syncthreads();

    auto commit2 = [&](const f32x16& ac, int mt, int t, int row, short* dst) {
#pragma unroll
        for (int g = 0; g < 4; ++g) {
            int o4 = obase + mt * 32 + 8 * g + 4 * lhi;
            int hi = swzH(t, o4);
            float4 h4 = *(float4*)&hrF2[hi];
            h4.x += fmaxf(ac[4*g+0], 0.f);
            h4.y += fmaxf(ac[4*g+1], 0.f);
            h4.z += fmaxf(ac[4*g+2], 0.f);
            h4.w += fmaxf(ac[4*g+3], 0.f);
            *(float4*)&hrF2[hi] = h4;
            *(uint2*)&dst[swzB(row, o4)] = make_uint2(packbf(h4.y, h4.x), packbf(h4.w, h4.z));
        }
    };

    int cur = 0;
    for (int it = 0; it < 123; ++it) {
        const short* src = img2 + cur * I2STRIDE;
        short*       dst = img2 + (cur ^ 1) * I2STRIDE;

        if (mainw) {
            f32x16 a0, a1;
#pragma unroll
            for (int g = 0; g < 4; ++g) {
                float4 b0 = *(const float4*)&cbS[obase + 8 * g + 4 * lhi];
                float4 b1 = *(const float4*)&cbS[obase + 32 + 8 * g + 4 * lhi];
                a0[4*g+0]=b0.x; a0[4*g+1]=b0.y; a0[4*g+2]=b0.z; a0[4*g+3]=b0.w;
                a1[4*g+0]=b1.x; a1[4*g+1]=b1.y; a1[4*g+2]=b1.z; a1[4*g+3]=b1.w;
            }
#pragma unroll
            for (int kk = 0; kk < 3; ++kk) {
                const int row = l31 + kk;
#pragma unroll
                for (int cb = 0; cb < 8; ++cb) {
                    short8 bf = *(const short8*)&src[swzB(row, cb * 16 + lhi * 8)];
                    a0 = __builtin_amdgcn_mfma_f32_32x32x16_bf16(aw[(kk*8+cb)*2+0], bf, a0, 0, 0, 0);
                    a1 = __builtin_amdgcn_mfma_f32_32x32x16_bf16(aw[(kk*8+cb)*2+1], bf, a1, 0, 0, 0);
                }
            }
            commit2(a0, 0, l31, l31 + 1, dst);
            commit2(a1, 1, l31, l31 + 1, dst);
        } else if (r == 0) {
            // appendix t'=32: taps 0 (row 32) and 1 (row 33); tap2 = zero pad (skipped)
            f32x16 a0, a1;
#pragma unroll
            for (int g = 0; g < 4; ++g) {
                float4 b0 = *(const float4*)&cbS[obase + 8 * g + 4 * lhi];
                float4 b1 = *(const float4*)&cbS[obase + 32 + 8 * g + 4 * lhi];
                a0[4*g+0]=b0.x; a0[4*g+1]=b0.y; a0[4*g+2]=b0.z; a0[4*g+3]=b0.w;
                a1[4*g+0]=b1.x; a1[4*g+1]=b1.y; a1[4*g+2]=b1.z; a1[4*g+3]=b1.w;
            }
#pragma unroll
            for (int kk = 0; kk < 2; ++kk) {
                int row = 32 + kk + l31;
                row = row > 34 ? 34 : row;   // rows >33 are zero
#pragma unroll
                for (int cb = 0; cb < 8; ++cb) {
                    short8 bf = *(const short8*)&src[swzB(row, cb * 16 + lhi * 8)];
                    a0 = __builtin_amdgcn_mfma_f32_32x32x16_bf16(aw[(kk*8+cb)*2+0], bf, a0, 0, 0, 0);
                    a1 = __builtin_amdgcn_mfma_f32_32x32x16_bf16(aw[(kk*8+cb)*2+1], bf, a1, 0, 0, 0);
                }
            }
            if (l31 == 0) {
                commit2(a0, 0, 32, 33, dst);
                commit2(a1, 1, 32, 33, dst);
            }
        }
        __syncthreads();
        cur ^= 1;
    }

    // output head: out[b, 4*t'+r, v]
    const int g4 = tid & 3;
    const int tt = tid >> 2;
    const int TR = (r == 0) ? 33 : 32;
    if (tt < TR) {
        float hq[32];
#pragma unroll
        for (int j = 0; j < 8; ++j) {
            float4 v = *(const float4*)&hrF2[swzH(tt, 32 * g4 + 4 * j)];
            hq[4*j+0] = v.x; hq[4*j+1] = v.y; hq[4*j+2] = v.z; hq[4*j+3] = v.w;
        }
#pragma unroll
        for (int v = 0; v < 10; ++v) {
            float s = 0.f;
#pragma unroll
            for (int i = 0; i < 16; ++i) {
                unsigned w = owP[v][16 * g4 + i];
                s += hq[2*i] * bflo(w) + hq[2*i+1] * bfhi(w);
            }
            s += __shfl_xor(s, 1);
            s += __shfl_xor(s, 2);
            if (g4 == 0) out[(b * 129 + 4 * tt + r) * 10 + v] = s + obS[v];
        }
    }
}

extern "C" void kernel_launch(void* const* d_in, const int* in_sizes, int n_in,
                              void* d_out, int out_size, void* d_ws, size_t ws_size,
                              hipStream_t stream) {
    const int*   x      = (const int*)d_in[0];
    const float* emb_w  = (const float*)d_in[1];
    const float* red_w  = (const float*)d_in[2];
    const float* red_b  = (const float*)d_in[3];
    const float* conv_w = (const float*)d_in[4];
    const float* conv_b = (const float*)d_in[5];
    const float* out_w  = (const float*)d_in[6];
    const float* out_b  = (const float*)d_in[7];
    (void)in_sizes; (void)n_in; (void)ws_size; (void)out_size;
    unsigned short* gw16 = (unsigned short*)d_ws;   // 32*129*128 bf16 = 1.03 MB
    vgt_phase1<<<32, 256, 0, stream>>>(x, emb_w, red_w, red_b, conv_w, conv_b, gw16);
    vgt_phase2<<<128, 256, 0, stream>>>(conv_w, conv_b, out_w, out_b, gw16, (float*)d_out);
}